// Round 15
// baseline (138.391 us; speedup 1.0000x reference)
//
#include <hip/hip_runtime.h>
#include <stdint.h>

#define M_PIX 8192
#define N_CB  16384
#define KD    256

typedef float f32x4 __attribute__((ext_vector_type(4)));
typedef int   i32x4 __attribute__((ext_vector_type(4)));
typedef int   i32x8 __attribute__((ext_vector_type(8)));
typedef unsigned long long ull;

// workspace layout (bytes)
#define OFF_CF8  (0ULL)            // codebook fp8 e4m3 (linear rows) : 4 MB
#define OFF_XF8  (4ULL << 20)      // x fp8 e4m3 (linear rows)        : 2 MB
#define OFF_CBSQ (6ULL << 20)      // ||c||^2 fp32                    : 64 KB
#define OFF_SLOT (7ULL << 20)      // float2 top2 [tile][pixel]       : 8 MB
#define WS_REQ   (15ULL << 20)

__device__ __forceinline__ unsigned int fkey(float s) {
  unsigned int f = __float_as_uint(s);
  return f ^ ((unsigned int)(((int)f) >> 31) | 0x80000000u);
}
// fp32 -> OCP e4m3fn, RNE, handles subnormals (step 2^-9), clamp 448
__device__ __forceinline__ unsigned char f2e4m3(float v) {
  float av = fminf(fabsf(v), 448.0f);
  const unsigned s = (__float_as_uint(v) >> 24) & 0x80u;
  unsigned m;
  if (av >= 0.015625f) {              // normal: round at mantissa bit 20
    unsigned u = __float_as_uint(av);
    u += 0x7FFFFu + ((u >> 20) & 1u);
    m = (((u >> 23) - 120u) << 3) | ((u >> 20) & 7u);
  } else {                            // subnormal
    m = (unsigned)(int)rintf(av * 512.0f);
  }
  return (unsigned char)(s | m);
}
__device__ __forceinline__ void gl_lds16(const unsigned char* g, char* l) {
  __builtin_amdgcn_global_load_lds(
      (const __attribute__((address_space(1))) unsigned int*)(const void*)g,
      (__attribute__((address_space(3))) unsigned int*)(void*)l,
      16, 0, 0);
}
// merge a SORTED pair (p <= q) into sorted state (v1 <= v2): 3 VALU
__device__ __forceinline__ void merge2(float p, float q, float& v1, float& v2) {
  const float M = fmaxf(v1, p);
  v1 = fminf(v1, p);
  v2 = fminf(fminf(v2, q), M);
}
// 32B fragment read from swizzled LDS: addr and addr^16
// (addr is already XOR-swizzled; bit4 of the pre-swizzle base is 0, so the
// second 16B of the logical 32B chunk lives at addr^16).
__device__ __forceinline__ i32x8 ld32(const char* p, int addr) {
  const i32x4 lo = *(const i32x4*)(const void*)(p + addr);
  const i32x4 hi = *(const i32x4*)(const void*)(p + (addr ^ 16));
  return (i32x8){lo.x, lo.y, lo.z, lo.w, hi.x, hi.y, hi.z, hi.w};
}

// ---------------- kernel 1: fp32 -> fp8 e4m3 linear rows + cb norms ---------
__global__ __launch_bounds__(256) void prep_kernel(
    const float* __restrict__ x, const float* __restrict__ cb,
    unsigned char* __restrict__ Cf8, unsigned char* __restrict__ Xf8,
    float* __restrict__ cbsq) {
  const int wid = threadIdx.x >> 6, lane = threadIdx.x & 63;
  const int row = blockIdx.x * 4 + wid;        // grid = (N_CB+M_PIX)/4
  const bool isCb = (row < N_CB);
  const int rowL = isCb ? row : row - N_CB;
  const float* src = (isCb ? cb : x) + (size_t)rowL * KD;
  const float4 v = ((const float4*)src)[lane];
  uchar4 pk;
  pk.x = f2e4m3(v.x); pk.y = f2e4m3(v.y); pk.z = f2e4m3(v.z); pk.w = f2e4m3(v.w);
  *(uchar4*)(void*)((isCb ? Cf8 : Xf8) + (size_t)rowL * KD + lane * 4) = pk;
  if (isCb) {
    float ss = v.x*v.x + v.y*v.y + v.z*v.z + v.w*v.w;   // fp32 norm
    #pragma unroll
    for (int off = 32; off > 0; off >>= 1) ss += __shfl_xor(ss, off);
    if (lane == 0) cbsq[rowL] = ss;
  }
}

// ---------------- kernel 2: MX-fp8 GEMM (identity scales) + per-tile top-2 --
// Base = R14 (verified best, 136.8 us total / ~57 us GEMM): two 128-col
// K-halves via global_load_lds into A,B 16 KB planes (row stride 128 B,
// XOR-swizzle byte^=(row&7)<<4 via pre-swizzled GLOBAL source, linear LDS
// dest); both halves' fragments pre-read to registers so staging/epilogue
// overlap MFMAs; cbsq hoisted under h1 MFMAs; mfma_scale identity scales;
// [tile][pixel] slots; 7-op owner network + sorted-pair merge scan.
// ONLY change this round (T5): s_setprio(1)/(0) around both register-only
// MFMA clusters. Mechanism: the R10/R11 schedule creates wave role
// diversity (staging + epilogue VALU issued around MFMA clusters; ~2.2
// co-resident blocks at unsynchronized phases) — priority keeps the matrix
// pipe fed when co-resident waves issue memory/VALU ops. Catalog: +21-39%
// when phase-split exists (m218b/m224), ~0 on lockstep (m190). Zero
// numeric effect -> output bit-identical.

__global__ __launch_bounds__(256, 3) void gemm_top2_kernel(
    const unsigned char* __restrict__ Xf8, const unsigned char* __restrict__ Cf8,
    const float* __restrict__ cbsq, float2* __restrict__ slots) {
  __shared__ __align__(16) char smem[36864];
  char* A_s = smem;                       // 16 KB [128][128B]
  char* B_s = smem + 16384;               // 16 KB
  float* v1p = (float*)smem;              // overlay: [128][36] = 18432 B
  float* v2p = (float*)(smem + 18432);    // overlay: [128][36]

  const int tid = threadIdx.x;
  const int wid = tid >> 6, lane = tid & 63;
  const int wy = wid >> 1, wx = wid & 1;
  const int q = lane >> 4, c = lane & 15;

  // m-outer / n-inner per XCD: 16-block sweeps share one A-tile + B-strip
  const int bx = blockIdx.x & 7, bg = blockIdx.x >> 3;
  const int mt = bg >> 4;               // 0..63
  const int nt = bx * 16 + (bg & 15);   // 0..127
  const int m0 = mt * 128, n0 = nt * 128;

  // per-lane swizzled LDS frag byte addresses. All frag rows == c (mod 8),
  // so the swizzle term is one per-lane constant.
  const int swz = (c & 7) << 4;
  int aaddr[4], baddr[4];
  #pragma unroll
  for (int i = 0; i < 4; i++) {
    aaddr[i] = (((wy * 64 + i * 16 + c) * 128) + q * 32) ^ swz;
    baddr[i] = ((((wx * 64 + i * 16 + c) * 128) + q * 32) ^ swz) + 16384;
  }

  const f32x4 zf = {0.f, 0.f, 0.f, 0.f};
  f32x4 acc[4][4];
  #pragma unroll
  for (int i = 0; i < 4; i++)
    #pragma unroll
    for (int j = 0; j < 4; j++) acc[i][j] = zf;

  // staging: inverse-swizzled global source, linear LDS dest
  const int srow8 = lane >> 3;                       // row within 8-row chunk
  const int sgb = ((lane & 7) ^ srow8) * 16;         // pre-swizzled 16B slot

  // ---- stage half 0 ----
  #pragma unroll
  for (int j = 0; j < 4; j++) {           // 16 chunks of 1 KB per operand
    const int chunk = j * 4 + wid;        // wave-uniform
    const int row = chunk * 8 + srow8;
    gl_lds16(Xf8 + (size_t)(m0 + row) * KD + sgb, A_s + chunk * 1024);
    gl_lds16(Cf8 + (size_t)(n0 + row) * KD + sgb, B_s + chunk * 1024);
  }
  __syncthreads();                        // h0 landed (vmcnt drain + barrier)

  // ---- pre-read ALL half-0 fragments into registers ----
  i32x8 af0[4], bf0[4];
  #pragma unroll
  for (int mi = 0; mi < 4; mi++) af0[mi] = ld32(smem, aaddr[mi]);
  #pragma unroll
  for (int ni = 0; ni < 4; ni++) bf0[ni] = ld32(smem, baddr[ni]);
  __builtin_amdgcn_sched_barrier(0);      // pin reads before the barrier
  __syncthreads();                        // all waves done reading -> planes dead

  // ---- stage half 1 into the same planes (flies under MFMA below) ----
  #pragma unroll
  for (int j = 0; j < 4; j++) {
    const int chunk = j * 4 + wid;
    const int row = chunk * 8 + srow8;
    gl_lds16(Xf8 + (size_t)(m0 + row) * KD + sgb + 128, A_s + chunk * 1024);
    gl_lds16(Cf8 + (size_t)(n0 + row) * KD + sgb + 128, B_s + chunk * 1024);
  }
  __builtin_amdgcn_sched_barrier(0);      // stage issued before MFMA

  // ---- MFMA half 0 (register-only; overlaps half-1 staging) ----
  __builtin_amdgcn_s_setprio(1);          // T5: favor the MFMA wave
  #pragma unroll
  for (int mi = 0; mi < 4; mi++)
    #pragma unroll
    for (int ni = 0; ni < 4; ni++)
      acc[mi][ni] = __builtin_amdgcn_mfma_scale_f32_16x16x128_f8f6f4(
          af0[mi], bf0[ni], acc[mi][ni], 0, 0,
          0, 0x7F7F7F7F,    // A scales: E8M0 127 = 1.0
          0, 0x7F7F7F7F);   // B scales: identity
  __builtin_amdgcn_s_setprio(0);
  __builtin_amdgcn_sched_barrier(0);      // MFMAs stay before the drain
  __syncthreads();                        // h1 landed (vmcnt drain + barrier)

  // ---- cbsq loads issued NOW: latency hides under h1 MFMAs ----
  float cs[4]; unsigned colp[4];
  #pragma unroll
  for (int ni = 0; ni < 4; ni++) {
    colp[ni] = wx * 64 + ni * 16 + c;
    cs[ni] = cbsq[n0 + colp[ni]];
  }

  // ---- pre-read ALL half-1 fragments into registers (af0/bf0 recycled) ----
  #pragma unroll
  for (int mi = 0; mi < 4; mi++) af0[mi] = ld32(smem, aaddr[mi]);
  #pragma unroll
  for (int ni = 0; ni < 4; ni++) bf0[ni] = ld32(smem, baddr[ni]);
  __builtin_amdgcn_sched_barrier(0);      // pin reads before the barrier
  __syncthreads();                        // all reads done -> planes dead (overlay OK)

  // ---- MFMA half 1 (register-only; owner phases overlap across waves) ----
  __builtin_amdgcn_s_setprio(1);          // T5
  #pragma unroll
  for (int mi = 0; mi < 4; mi++)
    #pragma unroll
    for (int ni = 0; ni < 4; ni++)
      acc[mi][ni] = __builtin_amdgcn_mfma_scale_f32_16x16x128_f8f6f4(
          af0[mi], bf0[ni], acc[mi][ni], 0, 0,
          0, 0x7F7F7F7F, 0, 0x7F7F7F7F);
  __builtin_amdgcn_s_setprio(0);

  const float FINF = __uint_as_float(0x7F800000u);

  // owner phase: C/D layout col=lane&15, row=q*4+reg (m89/m91); col packed
  // into low 7 mantissa bits (|err|<=0.008, absorbed by k3 threshold).
  // top-2-of-4 via 7-op sorting network.
  #pragma unroll
  for (int mi = 0; mi < 4; mi++) {
    #pragma unroll
    for (int r = 0; r < 4; r++) {
      float k[4];
      #pragma unroll
      for (int ni = 0; ni < 4; ni++) {
        const float s = fmaf(-2.f, acc[mi][ni][r], cs[ni]);
        k[ni] = __uint_as_float((__float_as_uint(s) & 0xFFFFFF80u) | colp[ni]);
      }
      const float m1 = fminf(k[0], k[1]), M1 = fmaxf(k[0], k[1]);
      const float m2 = fminf(k[2], k[3]), M2 = fmaxf(k[2], k[3]);
      const float v1 = fminf(m1, m2);
      const float v2 = fminf(fmaxf(m1, m2), fminf(M1, M2));
      const int row = wy * 64 + mi * 16 + q * 4 + r;
      const int slot = wx * 16 + c;
      v1p[row * 36 + slot] = v1;
      v2p[row * 36 + slot] = v2;
    }
  }
  __syncthreads();

  // scan: 2 threads/row over 16 SORTED pairs each (3 VALU/pair), 1 shuffle
  // merge across the two halves.
  {
    const int srow = tid >> 1, half = tid & 1;
    float v1 = FINF, v2 = FINF;
    #pragma unroll
    for (int jj = 0; jj < 4; jj++) {
      const float4 a = *(const float4*)(const void*)(v1p + srow * 36 + half * 16 + jj * 4);
      const float4 b = *(const float4*)(const void*)(v2p + srow * 36 + half * 16 + jj * 4);
      merge2(a.x, b.x, v1, v2);
      merge2(a.y, b.y, v1, v2);
      merge2(a.z, b.z, v1, v2);
      merge2(a.w, b.w, v1, v2);
    }
    const float b1 = __shfl_xor(v1, 1), b2 = __shfl_xor(v2, 1);
    const float hi = fmaxf(v1, b1);
    v1 = fminf(v1, b1);
    v2 = fminf(fminf(v2, b2), hi);
    if (!half)
      slots[(size_t)nt * M_PIX + m0 + srow] = make_float2(v1, v2);
  }
}

// ---------------- kernel 3: global min + group-parallel exact rescore -------
// FROZEN at R12's verified version. Candidates with score < min+10 are
// rescored exactly in fp32, 4 AT A TIME by the wave's four 16-lane groups
// (lane lg holds 16 x-/cb-elements; 4-step intra-group reduce). The winning
// candidate's cb row is cached in the winning group's registers during
// rescore, so the final dependent cb[w] gather is deleted. Key semantics:
// fkey(sv)<<32|ij, distinct ij -> unique winner, tie -> lowest idx.
__global__ __launch_bounds__(256) void reduce_rescore_gather(
    const float* __restrict__ x, const float* __restrict__ cb,
    const float* __restrict__ cbsq, const float2* __restrict__ slots,
    float* __restrict__ out) {
  const int wid = threadIdx.x >> 6, lane = threadIdx.x & 63;
  const int pixel = blockIdx.x * 4 + wid;     // grid = 8192/4
  const int g = lane >> 4, lg = lane & 15;    // four 16-lane groups

  const float2 sA = slots[(size_t)lane * M_PIX + pixel];
  const float2 sB = slots[(size_t)(64 + lane) * M_PIX + pixel];
  const float sc[4] = {sA.x, sA.y, sB.x, sB.y};
  float mn = fminf(fminf(sc[0], sc[1]), fminf(sc[2], sc[3]));
  #pragma unroll
  for (int off = 1; off < 64; off <<= 1) mn = fminf(mn, __shfl_xor(mn, off));
  const float thr = mn + 10.0f;

  // lane lg holds x[pixel][lg*16 .. lg*16+16)
  float4 xv16[4];
  #pragma unroll
  for (int k = 0; k < 4; k++)
    xv16[k] = ((const float4*)x)[(size_t)pixel * 64 + lg * 4 + k];

  const float4 z4 = make_float4(0.f, 0.f, 0.f, 0.f);
  ull best = ~0ULL;
  float4 wc[4] = {z4, z4, z4, z4};            // winner-row cache (lane slice)

  #pragma unroll
  for (int j = 0; j < 4; j++) {               // j static -> sc[j] static
    ull mask = __ballot(sc[j] < thr);         // wave-uniform
    while (mask) {
      // pop up to 4 candidates; group gg takes the gg-th (uniform control)
      int mysrc = -1;
      #pragma unroll
      for (int gg = 0; gg < 4; gg++) {
        if (mask) {
          const int s = (int)__ffsll((long long)mask) - 1;
          mask &= mask - 1;
          if (gg == g) mysrc = s;             // per-lane select, static gg
        }
      }
      const bool act = mysrc >= 0;
      const int srcs = act ? mysrc : 0;
      const float val = __shfl(sc[j], srcs);  // group-uniform src
      const unsigned ij = (unsigned)(((j >> 1) * 64 + srcs) * 128) +
                          (__float_as_uint(val) & 127u);
      float4 cv[4] = {z4, z4, z4, z4};
      float csq = 0.f;
      if (act) {
        #pragma unroll
        for (int k = 0; k < 4; k++)
          cv[k] = ((const float4*)cb)[(size_t)ij * 64 + lg * 4 + k];
        csq = cbsq[ij];
      }
      float d = cv[0].x*xv16[0].x + cv[0].y*xv16[0].y
              + cv[0].z*xv16[0].z + cv[0].w*xv16[0].w;
      d += cv[1].x*xv16[1].x + cv[1].y*xv16[1].y
         + cv[1].z*xv16[1].z + cv[1].w*xv16[1].w;
      d += cv[2].x*xv16[2].x + cv[2].y*xv16[2].y
         + cv[2].z*xv16[2].z + cv[2].w*xv16[2].w;
      d += cv[3].x*xv16[3].x + cv[3].y*xv16[3].y
         + cv[3].z*xv16[3].z + cv[3].w*xv16[3].w;
      #pragma unroll
      for (int off = 1; off < 16; off <<= 1) d += __shfl_xor(d, off);
      const float sv = fmaf(-2.f, d, csq);
      const ull key = act ? (((ull)fkey(sv) << 32) | ij) : ~0ULL;
      if (key < best) {
        best = key;
        wc[0] = cv[0]; wc[1] = cv[1]; wc[2] = cv[2]; wc[3] = cv[3];
      }
    }
  }

  // merge the 4 groups' bests (keys distinct -> unique winner)
  ull gb = best;
  {
    const ull o1 = __shfl_xor(gb, 16); gb = o1 < gb ? o1 : gb;
    const ull o2 = __shfl_xor(gb, 32); gb = o2 < gb ? o2 : gb;
  }
  if (best == gb) {                           // exactly one group's 16 lanes
    #pragma unroll
    for (int k = 0; k < 4; k++)
      ((float4*)out)[(size_t)pixel * 64 + lg * 4 + k] = wc[k];
  }
}

// ---------------- fallback (ws too small): exact fp32 scan ------------------
__global__ __launch_bounds__(256) void fallback_kernel(
    const float* __restrict__ x, const float* __restrict__ cb,
    float* __restrict__ out) {
  __shared__ float xs[256];
  __shared__ unsigned long long keys[4];
  __shared__ int widx;
  const int p = blockIdx.x;
  const int tid = threadIdx.x, wid = tid >> 6, lane = tid & 63;
  xs[tid] = x[(size_t)p * KD + tid];
  __syncthreads();
  const float4 xv = ((const float4*)xs)[lane];
  float bestS = 3.4e38f; int bestI = 0;
  for (int k = wid; k < N_CB; k += 4) {
    const float4 cv = ((const float4*)cb)[(size_t)k * 64 + lane];
    float t = cv.x*(cv.x - 2.f*xv.x) + cv.y*(cv.y - 2.f*xv.y)
            + cv.z*(cv.z - 2.f*xv.z) + cv.w*(cv.w - 2.f*xv.w);
    #pragma unroll
    for (int off = 1; off < 64; off <<= 1) t += __shfl_xor(t, off);
    if (t < bestS) { bestS = t; bestI = k; }
  }
  if (lane == 0)
    keys[wid] = ((unsigned long long)fkey(bestS) << 32) | (unsigned int)bestI;
  __syncthreads();
  if (tid == 0) {
    unsigned long long m = keys[0];
    for (int i = 1; i < 4; i++) if (keys[i] < m) m = keys[i];
    widx = (int)(unsigned int)(m & 0xFFFFFFFFULL);
  }
  __syncthreads();
  out[(size_t)p * KD + tid] = cb[(size_t)widx * KD + tid];
}

extern "C" void kernel_launch(void* const* d_in, const int* in_sizes, int n_in,
                              void* d_out, int out_size, void* d_ws, size_t ws_size,
                              hipStream_t stream) {
  const float* x  = (const float*)d_in[0];   // [8192,256]
  const float* cb = (const float*)d_in[1];   // [16384,256]
  float* out = (float*)d_out;                // [8192,256]

  if (ws_size < WS_REQ) {
    fallback_kernel<<<M_PIX, 256, 0, stream>>>(x, cb, out);
    return;
  }

  char* ws = (char*)d_ws;
  unsigned char* Cf8 = (unsigned char*)(ws + OFF_CF8);
  unsigned char* Xf8 = (unsigned char*)(ws + OFF_XF8);
  float* cbsq        = (float*)(ws + OFF_CBSQ);
  float2* slots      = (float2*)(ws + OFF_SLOT);

  prep_kernel<<<(N_CB + M_PIX) / 4, 256, 0, stream>>>(x, cb, Cf8, Xf8, cbsq);
  gemm_top2_kernel<<<M_PIX, 256, 0, stream>>>(Xf8, Cf8, cbsq, slots);
  reduce_rescore_gather<<<M_PIX / 4, 256, 0, stream>>>(x, cb, cbsq, slots, out);
}

// Round 16
// 136.065 us; speedup vs baseline: 1.0171x; 1.0171x over previous
//
#include <hip/hip_runtime.h>
#include <stdint.h>

#define M_PIX 8192
#define N_CB  16384
#define KD    256

typedef float f32x4 __attribute__((ext_vector_type(4)));
typedef int   i32x4 __attribute__((ext_vector_type(4)));
typedef int   i32x8 __attribute__((ext_vector_type(8)));
typedef unsigned long long ull;

// workspace layout (bytes)
#define OFF_CF8  (0ULL)            // codebook fp8 e4m3 (linear rows) : 4 MB
#define OFF_XF8  (4ULL << 20)      // x fp8 e4m3 (linear rows)        : 2 MB
#define OFF_CBSQ (6ULL << 20)      // ||c||^2 fp32                    : 64 KB
#define OFF_SLOT (7ULL << 20)      // float2 top2 [tile][pixel]       : 8 MB
#define WS_REQ   (15ULL << 20)

__device__ __forceinline__ unsigned int fkey(float s) {
  unsigned int f = __float_as_uint(s);
  return f ^ ((unsigned int)(((int)f) >> 31) | 0x80000000u);
}
// fp32 -> OCP e4m3fn, RNE, handles subnormals (step 2^-9), clamp 448
__device__ __forceinline__ unsigned char f2e4m3(float v) {
  float av = fminf(fabsf(v), 448.0f);
  const unsigned s = (__float_as_uint(v) >> 24) & 0x80u;
  unsigned m;
  if (av >= 0.015625f) {              // normal: round at mantissa bit 20
    unsigned u = __float_as_uint(av);
    u += 0x7FFFFu + ((u >> 20) & 1u);
    m = (((u >> 23) - 120u) << 3) | ((u >> 20) & 7u);
  } else {                            // subnormal
    m = (unsigned)(int)rintf(av * 512.0f);
  }
  return (unsigned char)(s | m);
}
__device__ __forceinline__ void gl_lds16(const unsigned char* g, char* l) {
  __builtin_amdgcn_global_load_lds(
      (const __attribute__((address_space(1))) unsigned int*)(const void*)g,
      (__attribute__((address_space(3))) unsigned int*)(void*)l,
      16, 0, 0);
}
// merge a SORTED pair (p <= q) into sorted state (v1 <= v2): 3 VALU
__device__ __forceinline__ void merge2(float p, float q, float& v1, float& v2) {
  const float M = fmaxf(v1, p);
  v1 = fminf(v1, p);
  v2 = fminf(fminf(v2, q), M);
}
// 32B fragment read from swizzled LDS: addr and addr^16
// (addr is already XOR-swizzled; bit4 of the pre-swizzle base is 0, so the
// second 16B of the logical 32B chunk lives at addr^16).
__device__ __forceinline__ i32x8 ld32(const char* p, int addr) {
  const i32x4 lo = *(const i32x4*)(const void*)(p + addr);
  const i32x4 hi = *(const i32x4*)(const void*)(p + (addr ^ 16));
  return (i32x8){lo.x, lo.y, lo.z, lo.w, hi.x, hi.y, hi.z, hi.w};
}

// ---------------- kernel 1: fp32 -> fp8 e4m3 linear rows + cb norms ---------
__global__ __launch_bounds__(256) void prep_kernel(
    const float* __restrict__ x, const float* __restrict__ cb,
    unsigned char* __restrict__ Cf8, unsigned char* __restrict__ Xf8,
    float* __restrict__ cbsq) {
  const int wid = threadIdx.x >> 6, lane = threadIdx.x & 63;
  const int row = blockIdx.x * 4 + wid;        // grid = (N_CB+M_PIX)/4
  const bool isCb = (row < N_CB);
  const int rowL = isCb ? row : row - N_CB;
  const float* src = (isCb ? cb : x) + (size_t)rowL * KD;
  const float4 v = ((const float4*)src)[lane];
  uchar4 pk;
  pk.x = f2e4m3(v.x); pk.y = f2e4m3(v.y); pk.z = f2e4m3(v.z); pk.w = f2e4m3(v.w);
  *(uchar4*)(void*)((isCb ? Cf8 : Xf8) + (size_t)rowL * KD + lane * 4) = pk;
  if (isCb) {
    float ss = v.x*v.x + v.y*v.y + v.z*v.z + v.w*v.w;   // fp32 norm
    #pragma unroll
    for (int off = 32; off > 0; off >>= 1) ss += __shfl_xor(ss, off);
    if (lane == 0) cbsq[rowL] = ss;
  }
}

// ---------------- kernel 2: MX-fp8 GEMM (identity scales) + per-tile top-2 --
// FINAL (R14 configuration, best measured 136.8 us total / ~57 us GEMM; T5
// setprio tested R15 -> null, reverted). Two 128-col K-halves via
// global_load_lds into A,B 16 KB planes (row stride 128 B, XOR-swizzle
// byte^=(row&7)<<4 via pre-swizzled GLOBAL source, linear LDS dest); both
// halves' fragments pre-read to registers so staging/epilogue overlap
// MFMAs; cbsq hoisted under h1 MFMAs; mfma_scale_f32_16x16x128_f8f6f4
// identity scales (E8M0 127) = plain fp8 GEMM at 2x the non-scaled rate;
// [tile][pixel] slots; 7-op owner network + sorted-pair merge scan.
// Structural constraint (15 rounds of evidence): per-block critical path
// ~9.4k cy at ~2.2 resident blocks/CU, invariant to LDS/VGPR capacity;
// deeper pipelining (dbuf-64K, reg-direct, hybrid, persistent, slim-plane,
// setprio) all tested and regressed or null.

__global__ __launch_bounds__(256, 3) void gemm_top2_kernel(
    const unsigned char* __restrict__ Xf8, const unsigned char* __restrict__ Cf8,
    const float* __restrict__ cbsq, float2* __restrict__ slots) {
  __shared__ __align__(16) char smem[36864];
  char* A_s = smem;                       // 16 KB [128][128B]
  char* B_s = smem + 16384;               // 16 KB
  float* v1p = (float*)smem;              // overlay: [128][36] = 18432 B
  float* v2p = (float*)(smem + 18432);    // overlay: [128][36]

  const int tid = threadIdx.x;
  const int wid = tid >> 6, lane = tid & 63;
  const int wy = wid >> 1, wx = wid & 1;
  const int q = lane >> 4, c = lane & 15;

  // m-outer / n-inner per XCD: 16-block sweeps share one A-tile + B-strip
  const int bx = blockIdx.x & 7, bg = blockIdx.x >> 3;
  const int mt = bg >> 4;               // 0..63
  const int nt = bx * 16 + (bg & 15);   // 0..127
  const int m0 = mt * 128, n0 = nt * 128;

  // per-lane swizzled LDS frag byte addresses. All frag rows == c (mod 8),
  // so the swizzle term is one per-lane constant.
  const int swz = (c & 7) << 4;
  int aaddr[4], baddr[4];
  #pragma unroll
  for (int i = 0; i < 4; i++) {
    aaddr[i] = (((wy * 64 + i * 16 + c) * 128) + q * 32) ^ swz;
    baddr[i] = ((((wx * 64 + i * 16 + c) * 128) + q * 32) ^ swz) + 16384;
  }

  const f32x4 zf = {0.f, 0.f, 0.f, 0.f};
  f32x4 acc[4][4];
  #pragma unroll
  for (int i = 0; i < 4; i++)
    #pragma unroll
    for (int j = 0; j < 4; j++) acc[i][j] = zf;

  // staging: inverse-swizzled global source, linear LDS dest
  const int srow8 = lane >> 3;                       // row within 8-row chunk
  const int sgb = ((lane & 7) ^ srow8) * 16;         // pre-swizzled 16B slot

  // ---- stage half 0 ----
  #pragma unroll
  for (int j = 0; j < 4; j++) {           // 16 chunks of 1 KB per operand
    const int chunk = j * 4 + wid;        // wave-uniform
    const int row = chunk * 8 + srow8;
    gl_lds16(Xf8 + (size_t)(m0 + row) * KD + sgb, A_s + chunk * 1024);
    gl_lds16(Cf8 + (size_t)(n0 + row) * KD + sgb, B_s + chunk * 1024);
  }
  __syncthreads();                        // h0 landed (vmcnt drain + barrier)

  // ---- pre-read ALL half-0 fragments into registers ----
  i32x8 af0[4], bf0[4];
  #pragma unroll
  for (int mi = 0; mi < 4; mi++) af0[mi] = ld32(smem, aaddr[mi]);
  #pragma unroll
  for (int ni = 0; ni < 4; ni++) bf0[ni] = ld32(smem, baddr[ni]);
  __builtin_amdgcn_sched_barrier(0);      // pin reads before the barrier
  __syncthreads();                        // all waves done reading -> planes dead

  // ---- stage half 1 into the same planes (flies under MFMA below) ----
  #pragma unroll
  for (int j = 0; j < 4; j++) {
    const int chunk = j * 4 + wid;
    const int row = chunk * 8 + srow8;
    gl_lds16(Xf8 + (size_t)(m0 + row) * KD + sgb + 128, A_s + chunk * 1024);
    gl_lds16(Cf8 + (size_t)(n0 + row) * KD + sgb + 128, B_s + chunk * 1024);
  }
  __builtin_amdgcn_sched_barrier(0);      // stage issued before MFMA

  // ---- MFMA half 0 (register-only; overlaps half-1 staging) ----
  #pragma unroll
  for (int mi = 0; mi < 4; mi++)
    #pragma unroll
    for (int ni = 0; ni < 4; ni++)
      acc[mi][ni] = __builtin_amdgcn_mfma_scale_f32_16x16x128_f8f6f4(
          af0[mi], bf0[ni], acc[mi][ni], 0, 0,
          0, 0x7F7F7F7F,    // A scales: E8M0 127 = 1.0
          0, 0x7F7F7F7F);   // B scales: identity
  __builtin_amdgcn_sched_barrier(0);      // MFMAs stay before the drain
  __syncthreads();                        // h1 landed (vmcnt drain + barrier)

  // ---- cbsq loads issued NOW: latency hides under h1 MFMAs ----
  float cs[4]; unsigned colp[4];
  #pragma unroll
  for (int ni = 0; ni < 4; ni++) {
    colp[ni] = wx * 64 + ni * 16 + c;
    cs[ni] = cbsq[n0 + colp[ni]];
  }

  // ---- pre-read ALL half-1 fragments into registers (af0/bf0 recycled) ----
  #pragma unroll
  for (int mi = 0; mi < 4; mi++) af0[mi] = ld32(smem, aaddr[mi]);
  #pragma unroll
  for (int ni = 0; ni < 4; ni++) bf0[ni] = ld32(smem, baddr[ni]);
  __builtin_amdgcn_sched_barrier(0);      // pin reads before the barrier
  __syncthreads();                        // all reads done -> planes dead (overlay OK)

  // ---- MFMA half 1 (register-only; owner phases overlap across waves) ----
  #pragma unroll
  for (int mi = 0; mi < 4; mi++)
    #pragma unroll
    for (int ni = 0; ni < 4; ni++)
      acc[mi][ni] = __builtin_amdgcn_mfma_scale_f32_16x16x128_f8f6f4(
          af0[mi], bf0[ni], acc[mi][ni], 0, 0,
          0, 0x7F7F7F7F, 0, 0x7F7F7F7F);

  const float FINF = __uint_as_float(0x7F800000u);

  // owner phase: C/D layout col=lane&15, row=q*4+reg (m89/m91); col packed
  // into low 7 mantissa bits (|err|<=0.008, absorbed by k3 threshold).
  // top-2-of-4 via 7-op sorting network.
  #pragma unroll
  for (int mi = 0; mi < 4; mi++) {
    #pragma unroll
    for (int r = 0; r < 4; r++) {
      float k[4];
      #pragma unroll
      for (int ni = 0; ni < 4; ni++) {
        const float s = fmaf(-2.f, acc[mi][ni][r], cs[ni]);
        k[ni] = __uint_as_float((__float_as_uint(s) & 0xFFFFFF80u) | colp[ni]);
      }
      const float m1 = fminf(k[0], k[1]), M1 = fmaxf(k[0], k[1]);
      const float m2 = fminf(k[2], k[3]), M2 = fmaxf(k[2], k[3]);
      const float v1 = fminf(m1, m2);
      const float v2 = fminf(fmaxf(m1, m2), fminf(M1, M2));
      const int row = wy * 64 + mi * 16 + q * 4 + r;
      const int slot = wx * 16 + c;
      v1p[row * 36 + slot] = v1;
      v2p[row * 36 + slot] = v2;
    }
  }
  __syncthreads();

  // scan: 2 threads/row over 16 SORTED pairs each (3 VALU/pair), 1 shuffle
  // merge across the two halves.
  {
    const int srow = tid >> 1, half = tid & 1;
    float v1 = FINF, v2 = FINF;
    #pragma unroll
    for (int jj = 0; jj < 4; jj++) {
      const float4 a = *(const float4*)(const void*)(v1p + srow * 36 + half * 16 + jj * 4);
      const float4 b = *(const float4*)(const void*)(v2p + srow * 36 + half * 16 + jj * 4);
      merge2(a.x, b.x, v1, v2);
      merge2(a.y, b.y, v1, v2);
      merge2(a.z, b.z, v1, v2);
      merge2(a.w, b.w, v1, v2);
    }
    const float b1 = __shfl_xor(v1, 1), b2 = __shfl_xor(v2, 1);
    const float hi = fmaxf(v1, b1);
    v1 = fminf(v1, b1);
    v2 = fminf(fminf(v2, b2), hi);
    if (!half)
      slots[(size_t)nt * M_PIX + m0 + srow] = make_float2(v1, v2);
  }
}

// ---------------- kernel 3: global min + group-parallel exact rescore -------
// FROZEN at R12's verified version. Candidates with score < min+10 are
// rescored exactly in fp32, 4 AT A TIME by the wave's four 16-lane groups
// (lane lg holds 16 x-/cb-elements; 4-step intra-group reduce). The winning
// candidate's cb row is cached in the winning group's registers during
// rescore, so the final dependent cb[w] gather is deleted. Key semantics:
// fkey(sv)<<32|ij, distinct ij -> unique winner, tie -> lowest idx.
__global__ __launch_bounds__(256) void reduce_rescore_gather(
    const float* __restrict__ x, const float* __restrict__ cb,
    const float* __restrict__ cbsq, const float2* __restrict__ slots,
    float* __restrict__ out) {
  const int wid = threadIdx.x >> 6, lane = threadIdx.x & 63;
  const int pixel = blockIdx.x * 4 + wid;     // grid = 8192/4
  const int g = lane >> 4, lg = lane & 15;    // four 16-lane groups

  const float2 sA = slots[(size_t)lane * M_PIX + pixel];
  const float2 sB = slots[(size_t)(64 + lane) * M_PIX + pixel];
  const float sc[4] = {sA.x, sA.y, sB.x, sB.y};
  float mn = fminf(fminf(sc[0], sc[1]), fminf(sc[2], sc[3]));
  #pragma unroll
  for (int off = 1; off < 64; off <<= 1) mn = fminf(mn, __shfl_xor(mn, off));
  const float thr = mn + 10.0f;

  // lane lg holds x[pixel][lg*16 .. lg*16+16)
  float4 xv16[4];
  #pragma unroll
  for (int k = 0; k < 4; k++)
    xv16[k] = ((const float4*)x)[(size_t)pixel * 64 + lg * 4 + k];

  const float4 z4 = make_float4(0.f, 0.f, 0.f, 0.f);
  ull best = ~0ULL;
  float4 wc[4] = {z4, z4, z4, z4};            // winner-row cache (lane slice)

  #pragma unroll
  for (int j = 0; j < 4; j++) {               // j static -> sc[j] static
    ull mask = __ballot(sc[j] < thr);         // wave-uniform
    while (mask) {
      // pop up to 4 candidates; group gg takes the gg-th (uniform control)
      int mysrc = -1;
      #pragma unroll
      for (int gg = 0; gg < 4; gg++) {
        if (mask) {
          const int s = (int)__ffsll((long long)mask) - 1;
          mask &= mask - 1;
          if (gg == g) mysrc = s;             // per-lane select, static gg
        }
      }
      const bool act = mysrc >= 0;
      const int srcs = act ? mysrc : 0;
      const float val = __shfl(sc[j], srcs);  // group-uniform src
      const unsigned ij = (unsigned)(((j >> 1) * 64 + srcs) * 128) +
                          (__float_as_uint(val) & 127u);
      float4 cv[4] = {z4, z4, z4, z4};
      float csq = 0.f;
      if (act) {
        #pragma unroll
        for (int k = 0; k < 4; k++)
          cv[k] = ((const float4*)cb)[(size_t)ij * 64 + lg * 4 + k];
        csq = cbsq[ij];
      }
      float d = cv[0].x*xv16[0].x + cv[0].y*xv16[0].y
              + cv[0].z*xv16[0].z + cv[0].w*xv16[0].w;
      d += cv[1].x*xv16[1].x + cv[1].y*xv16[1].y
         + cv[1].z*xv16[1].z + cv[1].w*xv16[1].w;
      d += cv[2].x*xv16[2].x + cv[2].y*xv16[2].y
         + cv[2].z*xv16[2].z + cv[2].w*xv16[2].w;
      d += cv[3].x*xv16[3].x + cv[3].y*xv16[3].y
         + cv[3].z*xv16[3].z + cv[3].w*xv16[3].w;
      #pragma unroll
      for (int off = 1; off < 16; off <<= 1) d += __shfl_xor(d, off);
      const float sv = fmaf(-2.f, d, csq);
      const ull key = act ? (((ull)fkey(sv) << 32) | ij) : ~0ULL;
      if (key < best) {
        best = key;
        wc[0] = cv[0]; wc[1] = cv[1]; wc[2] = cv[2]; wc[3] = cv[3];
      }
    }
  }

  // merge the 4 groups' bests (keys distinct -> unique winner)
  ull gb = best;
  {
    const ull o1 = __shfl_xor(gb, 16); gb = o1 < gb ? o1 : gb;
    const ull o2 = __shfl_xor(gb, 32); gb = o2 < gb ? o2 : gb;
  }
  if (best == gb) {                           // exactly one group's 16 lanes
    #pragma unroll
    for (int k = 0; k < 4; k++)
      ((float4*)out)[(size_t)pixel * 64 + lg * 4 + k] = wc[k];
  }
}

// ---------------- fallback (ws too small): exact fp32 scan ------------------
__global__ __launch_bounds__(256) void fallback_kernel(
    const float* __restrict__ x, const float* __restrict__ cb,
    float* __restrict__ out) {
  __shared__ float xs[256];
  __shared__ unsigned long long keys[4];
  __shared__ int widx;
  const int p = blockIdx.x;
  const int tid = threadIdx.x, wid = tid >> 6, lane = tid & 63;
  xs[tid] = x[(size_t)p * KD + tid];
  __syncthreads();
  const float4 xv = ((const float4*)xs)[lane];
  float bestS = 3.4e38f; int bestI = 0;
  for (int k = wid; k < N_CB; k += 4) {
    const float4 cv = ((const float4*)cb)[(size_t)k * 64 + lane];
    float t = cv.x*(cv.x - 2.f*xv.x) + cv.y*(cv.y - 2.f*xv.y)
            + cv.z*(cv.z - 2.f*xv.z) + cv.w*(cv.w - 2.f*xv.w);
    #pragma unroll
    for (int off = 1; off < 64; off <<= 1) t += __shfl_xor(t, off);
    if (t < bestS) { bestS = t; bestI = k; }
  }
  if (lane == 0)
    keys[wid] = ((unsigned long long)fkey(bestS) << 32) | (unsigned int)bestI;
  __syncthreads();
  if (tid == 0) {
    unsigned long long m = keys[0];
    for (int i = 1; i < 4; i++) if (keys[i] < m) m = keys[i];
    widx = (int)(unsigned int)(m & 0xFFFFFFFFULL);
  }
  __syncthreads();
  out[(size_t)p * KD + tid] = cb[(size_t)widx * KD + tid];
}

extern "C" void kernel_launch(void* const* d_in, const int* in_sizes, int n_in,
                              void* d_out, int out_size, void* d_ws, size_t ws_size,
                              hipStream_t stream) {
  const float* x  = (const float*)d_in[0];   // [8192,256]
  const float* cb = (const float*)d_in[1];   // [16384,256]
  float* out = (float*)d_out;                // [8192,256]

  if (ws_size < WS_REQ) {
    fallback_kernel<<<M_PIX, 256, 0, stream>>>(x, cb, out);
    return;
  }

  char* ws = (char*)d_ws;
  unsigned char* Cf8 = (unsigned char*)(ws + OFF_CF8);
  unsigned char* Xf8 = (unsigned char*)(ws + OFF_XF8);
  float* cbsq        = (float*)(ws + OFF_CBSQ);
  float2* slots      = (float2*)(ws + OFF_SLOT);

  prep_kernel<<<(N_CB + M_PIX) / 4, 256, 0, stream>>>(x, cb, Cf8, Xf8, cbsq);
  gemm_top2_kernel<<<M_PIX, 256, 0, stream>>>(Xf8, Cf8, cbsq, slots);
  reduce_rescore_gather<<<M_PIX / 4, 256, 0, stream>>>(x, cb, cbsq, slots, out);
}